// Round 8
// baseline (146.563 us; speedup 1.0000x reference)
//
#include <hip/hip_runtime.h>
#include <math.h>

#define NN 8192
#define FIN 512
#define HD 128
#define CAP 128

typedef float f32x4 __attribute__((ext_vector_type(4)));

// ---------------------------------------------------------------------------
// K1 "front": heterogeneous kernel, block-granular INTERLEAVED split so every
// CU hosts both kinds of work (VALU-bound GEMM overlaps HBM-bound scan):
//   blocks with b%5==0 (512): GEMM tile of xl = x@Wl1 (gi<256) or xr = x@Wr1
//   all other blocks (2048):  adjacency scan -> nbr/degi/degf (1 row/wave)
//   block 2560:               fold wsm = {Wl2@Wd, Wr2@Wd, b2@Wd+bd}
// ---------------------------------------------------------------------------
__global__ __launch_bounds__(256) void k_front(
    const float* __restrict__ x, const float* __restrict__ Wl1,
    const float* __restrict__ Wr1, const float* __restrict__ adj,
    const float* __restrict__ Wl2, const float* __restrict__ Wr2,
    const float* __restrict__ b2, const float* __restrict__ Wd,
    const float* __restrict__ bd,
    float* __restrict__ xl, float* __restrict__ xr,
    int* __restrict__ nbr, int* __restrict__ degi, float* __restrict__ degf,
    float4* __restrict__ wsm)
{
    __shared__ float As[32][32];
    __shared__ float Bs[32][128];
    const int tid = threadIdx.x;
    const int b = blockIdx.x;

    if (b == 2560) {
        // ---------------- fold small weights ----------------
        const int t = tid;
        if (t < HD) {
            float l0 = 0, l1 = 0, l2 = 0, r0 = 0, r1 = 0, r2 = 0;
            for (int c = 0; c < HD; ++c) {
                const float w0 = Wd[c * 3 + 0], w1 = Wd[c * 3 + 1], w2 = Wd[c * 3 + 2];
                const float wl = Wl2[t * HD + c];
                const float wr = Wr2[t * HD + c];
                l0 = fmaf(wl, w0, l0); l1 = fmaf(wl, w1, l1); l2 = fmaf(wl, w2, l2);
                r0 = fmaf(wr, w0, r0); r1 = fmaf(wr, w1, r1); r2 = fmaf(wr, w2, r2);
            }
            wsm[t]       = make_float4(l0, l1, l2, 0.f);
            wsm[128 + t] = make_float4(r0, r1, r2, 0.f);
            if (t == 0) {
                float c0 = bd[0], c1 = bd[1], c2 = bd[2];
                for (int c = 0; c < HD; ++c) {
                    c0 = fmaf(b2[c], Wd[c * 3 + 0], c0);
                    c1 = fmaf(b2[c], Wd[c * 3 + 1], c1);
                    c2 = fmaf(b2[c], Wd[c * 3 + 2], c2);
                }
                wsm[256] = make_float4(c0, c1, c2, 0.f);
            }
        }
    } else if (b % 5 == 0) {
        // ---------------- GEMM: 32x128 tile, K=512 ----------------
        const int gi = b / 5;                       // 0..511
        const float* W = (gi < 256) ? Wl1 : Wr1;
        float* Cout    = (gi < 256) ? xl  : xr;
        const int row0 = (gi & 255) * 32;
        const int rg = tid >> 5, cg = tid & 31;
        const int ar = tid >> 3, ak = (tid & 7) * 4;
        const int bk = tid >> 5, bc = (tid & 31) * 4;
        float acc[4][4] = {};
        for (int ch = 0; ch < FIN / 32; ++ch) {
            const int kc = ch * 32;
            __syncthreads();
            const float4 va = *(const float4*)(x + (size_t)(row0 + ar) * FIN + kc + ak);
            As[ak + 0][ar] = va.x; As[ak + 1][ar] = va.y;
            As[ak + 2][ar] = va.z; As[ak + 3][ar] = va.w;
            #pragma unroll
            for (int it = 0; it < 4; ++it)
                *(float4*)&Bs[bk + 8 * it][bc] =
                    *(const float4*)(W + (size_t)(kc + bk + 8 * it) * HD + bc);
            __syncthreads();
            #pragma unroll
            for (int k = 0; k < 32; ++k) {
                const float4 a4 = *(const float4*)&As[k][rg * 4];
                const float4 b4 = *(const float4*)&Bs[k][cg * 4];
                const float av[4] = {a4.x, a4.y, a4.z, a4.w};
                const float bv[4] = {b4.x, b4.y, b4.z, b4.w};
                #pragma unroll
                for (int a = 0; a < 4; ++a)
                    #pragma unroll
                    for (int bb = 0; bb < 4; ++bb)
                        acc[a][bb] = fmaf(av[a], bv[bb], acc[a][bb]);
            }
        }
        #pragma unroll
        for (int a = 0; a < 4; ++a)
            *(float4*)(Cout + (size_t)(row0 + rg * 4 + a) * HD + cg * 4) =
                make_float4(acc[a][0], acc[a][1], acc[a][2], acc[a][3]);
    } else {
        // ---------------- adjacency scan: 1 row per 64-lane wave ----------
        const int si = b - b / 5 - 1;               // 0..2047 scan block index
        const int w = tid >> 6, lane = tid & 63;
        const int i = si * 4 + w;
        int* lst = nbr + (size_t)i * CAP;
        const f32x4* row = (const f32x4*)(adj + (size_t)i * NN);
        const unsigned long long lmask = (1ull << lane) - 1ull;
        int cnt = 0;
        for (int it = 0; it < NN / 256; ++it) {   // 32 iters, 1 KB/wave each
            const f32x4 a = __builtin_nontemporal_load(&row[it * 64 + lane]);
            const float vals[4] = {a.x, a.y, a.z, a.w};
            #pragma unroll
            for (int e = 0; e < 4; ++e) {
                const bool nz = (vals[e] != 0.0f);
                const unsigned long long m = __ballot(nz);
                if (nz) {
                    const int p = cnt + (int)__popcll(m & lmask);
                    if (p < CAP) lst[p] = (it * 64 + lane) * 4 + e;
                }
                cnt += (int)__popcll(m);
            }
        }
        if (lane == 0) {
            degi[i] = cnt < CAP ? cnt : CAP;
            degf[i] = fmaxf((float)cnt, 1.0f);
        }
    }
}

// ---------------------------------------------------------------------------
// K2: one 64-lane wave per row i. Gather restructured so each float4 load
// covers TWO neighbor rows (lanes 0-31: even-indexed neighbor, lanes 32-63:
// odd): full 1KB/wave transactions, 8 neighbors per unrolled iteration.
//   h = relu(mean_j xl[j,:] + xr[i,:] + b1)   (4 cols per lane, in registers)
//   u[i] = h @ Wld, v[i] = h @ Wrd            (reduced over 32 lanes)
// ---------------------------------------------------------------------------
__global__ __launch_bounds__(256) void k_agg_proj(
    const float* __restrict__ xl, const float* __restrict__ xr,
    const float* __restrict__ b1, const int* __restrict__ nbr,
    const int* __restrict__ degi, const float* __restrict__ degf,
    const float4* __restrict__ wsm, float4* __restrict__ u4,
    float4* __restrict__ v4)
{
    __shared__ int lists[4][CAP];
    const int w = threadIdx.x >> 6, lane = threadIdx.x & 63;
    const int half = lane >> 5;          // 0: even-indexed nbr, 1: odd
    const int cl = lane & 31;            // column group: cols cl*4 .. cl*4+3
    const int i = blockIdx.x * 4 + w;
    const int d = degi[i];
    const float inv = 1.0f / degf[i];
    const int* glst = nbr + (size_t)i * CAP;
    if (lane < d)      lists[w][lane]      = glst[lane];
    if (lane + 64 < d) lists[w][lane + 64] = glst[lane + 64];
    const int* lst = lists[w];   // wave-local producer/consumer: lgkmcnt suffices

    f32x4 s = {0.f, 0.f, 0.f, 0.f};
    for (int t = 0; t < d; t += 8) {     // 8 neighbors per iter, 4 loads in flight
        #pragma unroll
        for (int e = 0; e < 4; ++e) {
            const int idx = t + 2 * e + half;
            const bool ok = idx < d;
            const int j = ok ? lst[idx] : 0;
            const f32x4 a = ((const f32x4*)(xl + (size_t)j * HD))[cl];
            if (ok) s += a;
        }
    }
    // merge even/odd halves: lane l and l^32 hold the same column group
    s.x += __shfl_xor(s.x, 32);
    s.y += __shfl_xor(s.y, 32);
    s.z += __shfl_xor(s.z, 32);
    s.w += __shfl_xor(s.w, 32);

    const f32x4 rr = ((const f32x4*)(xr + (size_t)i * HD))[cl];
    const f32x4 bb = ((const f32x4*)b1)[cl];
    f32x4 h;
    h.x = fmaxf(fmaf(s.x, inv, rr.x + bb.x), 0.f);
    h.y = fmaxf(fmaf(s.y, inv, rr.y + bb.y), 0.f);
    h.z = fmaxf(fmaf(s.z, inv, rr.z + bb.z), 0.f);
    h.w = fmaxf(fmaf(s.w, inv, rr.w + bb.w), 0.f);

    const float4 w0 = wsm[cl * 4 + 0], w1 = wsm[cl * 4 + 1];
    const float4 w2 = wsm[cl * 4 + 2], w3 = wsm[cl * 4 + 3];
    const float4 q0 = wsm[128 + cl * 4 + 0], q1 = wsm[128 + cl * 4 + 1];
    const float4 q2 = wsm[128 + cl * 4 + 2], q3 = wsm[128 + cl * 4 + 3];
    float u0 = h.x * w0.x + h.y * w1.x + h.z * w2.x + h.w * w3.x;
    float u1 = h.x * w0.y + h.y * w1.y + h.z * w2.y + h.w * w3.y;
    float u2 = h.x * w0.z + h.y * w1.z + h.z * w2.z + h.w * w3.z;
    float v0 = h.x * q0.x + h.y * q1.x + h.z * q2.x + h.w * q3.x;
    float v1 = h.x * q0.y + h.y * q1.y + h.z * q2.y + h.w * q3.y;
    float v2 = h.x * q0.z + h.y * q1.z + h.z * q2.z + h.w * q3.z;
    // reduce over the 32 column-lanes (lanes 32-63 are duplicates of 0-31)
    #pragma unroll
    for (int off = 16; off; off >>= 1) {
        u0 += __shfl_xor(u0, off); u1 += __shfl_xor(u1, off); u2 += __shfl_xor(u2, off);
        v0 += __shfl_xor(v0, off); v1 += __shfl_xor(v1, off); v2 += __shfl_xor(v2, off);
    }
    if (lane == 0) {
        u4[i] = make_float4(u0, u1, u2, 0.f);
        v4[i] = make_float4(v0, v1, v2, 0.f);
    }
}

// ---------------------------------------------------------------------------
// K3: y[i] = mean_j u[j] + v[i] + c   (3-wide second-hop aggregation)
// ---------------------------------------------------------------------------
__global__ __launch_bounds__(256) void k_ycomb(
    const float4* __restrict__ u4, const float4* __restrict__ v4,
    const int* __restrict__ nbr, const int* __restrict__ degi,
    const float* __restrict__ degf, const float4* __restrict__ wsm,
    float4* __restrict__ y4)
{
    const int hw = threadIdx.x >> 5;
    const int lane = threadIdx.x & 31;
    const int i = blockIdx.x * 8 + hw;
    const int d = degi[i];
    const float inv = 1.0f / degf[i];
    const int* lst = nbr + (size_t)i * CAP;
    float s0 = 0.f, s1 = 0.f, s2 = 0.f;
    for (int base = 0; base + lane < d; base += 32) {
        const float4 u = u4[lst[base + lane]];
        s0 += u.x; s1 += u.y; s2 += u.z;
    }
    #pragma unroll
    for (int off = 16; off; off >>= 1) {
        s0 += __shfl_xor(s0, off); s1 += __shfl_xor(s1, off); s2 += __shfl_xor(s2, off);
    }
    if (lane == 0) {
        const float4 v = v4[i];
        const float4 c = wsm[256];
        y4[i] = make_float4(fmaf(s0, inv, v.x + c.x),
                            fmaf(s1, inv, v.y + c.y),
                            fmaf(s2, inv, v.z + c.z), 0.f);
    }
}

// ---------------------------------------------------------------------------
// K4: out[i,j] = ||y_i - y_j||, tiled 32 i x 1024 j per block.
// yi staged in LDS, 4 yj in registers, non-temporal float4 stores.
// ---------------------------------------------------------------------------
__global__ __launch_bounds__(256) void k_cdist(
    const float4* __restrict__ y4, float* __restrict__ out)
{
    __shared__ float4 yis[32];
    const int t = threadIdx.x;
    const int i0 = blockIdx.y * 32;
    if (t < 32) yis[t] = y4[i0 + t];
    __syncthreads();
    const int j0 = blockIdx.x * 1024 + t * 4;
    const float4 a0 = y4[j0 + 0], a1 = y4[j0 + 1];
    const float4 a2 = y4[j0 + 2], a3 = y4[j0 + 3];
    float* op = out + (size_t)i0 * NN + j0;
    #pragma unroll 4
    for (int ii = 0; ii < 32; ++ii) {
        const float4 yi = yis[ii];
        f32x4 r;
        { const float dx = yi.x - a0.x, dy = yi.y - a0.y, dz = yi.z - a0.z;
          r.x = sqrtf(fmaf(dx, dx, fmaf(dy, dy, dz * dz))); }
        { const float dx = yi.x - a1.x, dy = yi.y - a1.y, dz = yi.z - a1.z;
          r.y = sqrtf(fmaf(dx, dx, fmaf(dy, dy, dz * dz))); }
        { const float dx = yi.x - a2.x, dy = yi.y - a2.y, dz = yi.z - a2.z;
          r.z = sqrtf(fmaf(dx, dx, fmaf(dy, dy, dz * dz))); }
        { const float dx = yi.x - a3.x, dy = yi.y - a3.y, dz = yi.z - a3.z;
          r.w = sqrtf(fmaf(dx, dx, fmaf(dy, dy, dz * dz))); }
        __builtin_nontemporal_store(r, (f32x4*)op);
        op += NN;
    }
}

// ---------------------------------------------------------------------------
extern "C" void kernel_launch(void* const* d_in, const int* in_sizes, int n_in,
                              void* d_out, int out_size, void* d_ws, size_t ws_size,
                              hipStream_t stream) {
    const float* x   = (const float*)d_in[0];
    const float* adj = (const float*)d_in[1];
    const float* Wl1 = (const float*)d_in[2];
    const float* Wr1 = (const float*)d_in[3];
    const float* b1  = (const float*)d_in[4];
    const float* Wl2 = (const float*)d_in[5];
    const float* Wr2 = (const float*)d_in[6];
    const float* b2  = (const float*)d_in[7];
    const float* Wd  = (const float*)d_in[8];
    const float* bd  = (const float*)d_in[9];
    float* out = (float*)d_out;

    // ---- workspace layout (16B-aligned slots) ----
    char* ws = (char*)d_ws;
    const size_t nbr_b  = (size_t)NN * CAP * 4;    // 4 MB
    const size_t deg_b  = (size_t)NN * 4;          // 32 KB each
    const size_t vec_b  = (size_t)NN * 16;         // 128 KB each (u4,v4,y4)
    const size_t wsm_b  = 272 * 16;
    const size_t small_total = nbr_b + 2 * deg_b + 3 * vec_b + wsm_b;
    const size_t xl_b = (size_t)NN * HD * 4;       // 4 MB each

    size_t off = 0;
    int*    nbr  = (int*)(ws + off);    off += nbr_b;
    int*    degi = (int*)(ws + off);    off += deg_b;
    float*  degf = (float*)(ws + off);  off += deg_b;
    float4* u4   = (float4*)(ws + off); off += vec_b;
    float4* v4   = (float4*)(ws + off); off += vec_b;
    float4* y4   = (float4*)(ws + off); off += vec_b;
    float4* wsm  = (float4*)(ws + off); off += wsm_b;

    // xl/xr: in ws if it fits, else carve from d_out (dead before k_cdist).
    char* big = (ws_size >= small_total + 2 * xl_b) ? (ws + off) : (char*)d_out;
    float* xl = (float*)(big);
    float* xr = (float*)(big + xl_b);

    // ---- pipeline ----
    k_front<<<2561, 256, 0, stream>>>(
        x, Wl1, Wr1, adj, Wl2, Wr2, b2, Wd, bd,
        xl, xr, nbr, degi, degf, wsm);

    k_agg_proj<<<NN / 4, 256, 0, stream>>>(xl, xr, b1, nbr, degi, degf,
                                           wsm, u4, v4);

    k_ycomb<<<NN / 8, 256, 0, stream>>>(u4, v4, nbr, degi, degf, wsm, y4);

    k_cdist<<<dim3(NN / 1024, NN / 32), 256, 0, stream>>>(y4, out);
}

// Round 9
// 144.972 us; speedup vs baseline: 1.0110x; 1.0110x over previous
//
#include <hip/hip_runtime.h>
#include <math.h>

#define NN 8192
#define FIN 512
#define HD 128
#define CAP 128

typedef float f32x4 __attribute__((ext_vector_type(4)));

// ---------------------------------------------------------------------------
// K0: dense GEMMs + weight fold. Blocks 0-255: xl = x@Wl1. Blocks 256-511:
// xrb = x@Wr1 + b1 (bias folded into epilogue). Block 512: wsm fold
// {Wl2@Wd, Wr2@Wd, b2@Wd+bd}. Only these blocks pay the 20.5 KB GEMM LDS.
// ---------------------------------------------------------------------------
__global__ __launch_bounds__(256) void k_gemm(
    const float* __restrict__ x, const float* __restrict__ Wl1,
    const float* __restrict__ Wr1, const float* __restrict__ b1,
    const float* __restrict__ Wl2, const float* __restrict__ Wr2,
    const float* __restrict__ b2, const float* __restrict__ Wd,
    const float* __restrict__ bd,
    float* __restrict__ xl, float* __restrict__ xr,
    float4* __restrict__ wsm)
{
    __shared__ float As[32][32];
    __shared__ float Bs[32][128];
    const int tid = threadIdx.x;
    const int b = blockIdx.x;

    if (b == 512) {
        const int t = tid;
        if (t < HD) {
            float l0 = 0, l1 = 0, l2 = 0, r0 = 0, r1 = 0, r2 = 0;
            for (int c = 0; c < HD; ++c) {
                const float w0 = Wd[c * 3 + 0], w1 = Wd[c * 3 + 1], w2 = Wd[c * 3 + 2];
                const float wl = Wl2[t * HD + c];
                const float wr = Wr2[t * HD + c];
                l0 = fmaf(wl, w0, l0); l1 = fmaf(wl, w1, l1); l2 = fmaf(wl, w2, l2);
                r0 = fmaf(wr, w0, r0); r1 = fmaf(wr, w1, r1); r2 = fmaf(wr, w2, r2);
            }
            wsm[t]       = make_float4(l0, l1, l2, 0.f);
            wsm[128 + t] = make_float4(r0, r1, r2, 0.f);
            if (t == 0) {
                float c0 = bd[0], c1 = bd[1], c2 = bd[2];
                for (int c = 0; c < HD; ++c) {
                    c0 = fmaf(b2[c], Wd[c * 3 + 0], c0);
                    c1 = fmaf(b2[c], Wd[c * 3 + 1], c1);
                    c2 = fmaf(b2[c], Wd[c * 3 + 2], c2);
                }
                wsm[256] = make_float4(c0, c1, c2, 0.f);
            }
        }
        return;
    }

    const bool left = (b < 256);
    const float* W = left ? Wl1 : Wr1;
    float* Cout    = left ? xl  : xr;
    const int row0 = (b & 255) * 32;
    const int rg = tid >> 5, cg = tid & 31;
    const int ar = tid >> 3, ak = (tid & 7) * 4;
    const int bk = tid >> 5, bc = (tid & 31) * 4;
    float acc[4][4] = {};
    for (int ch = 0; ch < FIN / 32; ++ch) {
        const int kc = ch * 32;
        __syncthreads();
        const float4 va = *(const float4*)(x + (size_t)(row0 + ar) * FIN + kc + ak);
        As[ak + 0][ar] = va.x; As[ak + 1][ar] = va.y;
        As[ak + 2][ar] = va.z; As[ak + 3][ar] = va.w;
        #pragma unroll
        for (int it = 0; it < 4; ++it)
            *(float4*)&Bs[bk + 8 * it][bc] =
                *(const float4*)(W + (size_t)(kc + bk + 8 * it) * HD + bc);
        __syncthreads();
        #pragma unroll
        for (int k = 0; k < 32; ++k) {
            const float4 a4 = *(const float4*)&As[k][rg * 4];
            const float4 b4 = *(const float4*)&Bs[k][cg * 4];
            const float av[4] = {a4.x, a4.y, a4.z, a4.w};
            const float bv[4] = {b4.x, b4.y, b4.z, b4.w};
            #pragma unroll
            for (int a = 0; a < 4; ++a)
                #pragma unroll
                for (int bb = 0; bb < 4; ++bb)
                    acc[a][bb] = fmaf(av[a], bv[bb], acc[a][bb]);
        }
    }
    float4 bias = make_float4(0.f, 0.f, 0.f, 0.f);
    if (!left) bias = ((const float4*)b1)[cg];   // fold b1 into xr
    #pragma unroll
    for (int a = 0; a < 4; ++a)
        *(float4*)(Cout + (size_t)(row0 + rg * 4 + a) * HD + cg * 4) =
            make_float4(acc[a][0] + bias.x, acc[a][1] + bias.y,
                        acc[a][2] + bias.z, acc[a][3] + bias.w);
}

// ---------------------------------------------------------------------------
// K1: fused scan + gather-mean + projection. One 64-lane wave per row i.
//   phase 1: ballot-compact adj row i -> LDS list (+ write nbr/degi/degf
//            for K2). 2 KB LDS -> 8 blocks/CU, 2048 blocks = 1 full round.
//   phase 2: gather xl rows off the LDS list (2 rows per float4-load wave),
//            h = relu(mean*inv + xrb), u = h@Wld, v = h@Wrd -> u4, v4.
// Gathers (L2/L3) of early-finishing blocks overlap late blocks' HBM scans.
// ---------------------------------------------------------------------------
__global__ __launch_bounds__(256) void k_scanagg(
    const float* __restrict__ adj, const float* __restrict__ xl,
    const float* __restrict__ xrb, const float4* __restrict__ wsm,
    int* __restrict__ nbr, int* __restrict__ degi, float* __restrict__ degf,
    float4* __restrict__ u4, float4* __restrict__ v4)
{
    __shared__ int lists[4][CAP];
    const int w = threadIdx.x >> 6, lane = threadIdx.x & 63;
    const int i = blockIdx.x * 4 + w;
    int* lst = lists[w];

    // ---- phase 1: scan ----
    const f32x4* row = (const f32x4*)(adj + (size_t)i * NN);
    const unsigned long long lmask = (1ull << lane) - 1ull;
    int cnt = 0;
    for (int it = 0; it < NN / 256; ++it) {   // 32 iters, 1 KB/wave each
        const f32x4 a = __builtin_nontemporal_load(&row[it * 64 + lane]);
        const float vals[4] = {a.x, a.y, a.z, a.w};
        #pragma unroll
        for (int e = 0; e < 4; ++e) {
            const bool nz = (vals[e] != 0.0f);
            const unsigned long long m = __ballot(nz);
            if (nz) {
                const int p = cnt + (int)__popcll(m & lmask);
                if (p < CAP) lst[p] = (it * 64 + lane) * 4 + e;
            }
            cnt += (int)__popcll(m);
        }
    }
    const int d = cnt < CAP ? cnt : CAP;
    const float inv = 1.0f / fmaxf((float)cnt, 1.0f);
    // export for K2 (wave-local LDS -> lgkmcnt ordering suffices)
    if (lane < d)      nbr[(size_t)i * CAP + lane]      = lst[lane];
    if (lane + 64 < d) nbr[(size_t)i * CAP + lane + 64] = lst[lane + 64];
    if (lane == 0) { degi[i] = d; degf[i] = fmaxf((float)cnt, 1.0f); }

    // ---- phase 2: gather-mean + projection ----
    const int half = lane >> 5;          // 0: even-indexed nbr, 1: odd
    const int cl = lane & 31;            // column group: cols cl*4 .. cl*4+3
    f32x4 s = {0.f, 0.f, 0.f, 0.f};
    for (int t = 0; t < d; t += 8) {     // 8 neighbors/iter, 4 loads in flight
        #pragma unroll
        for (int e = 0; e < 4; ++e) {
            const int idx = t + 2 * e + half;
            const bool ok = idx < d;
            const int j = ok ? lst[idx] : 0;
            const f32x4 a = ((const f32x4*)(xl + (size_t)j * HD))[cl];
            if (ok) s += a;
        }
    }
    s.x += __shfl_xor(s.x, 32);
    s.y += __shfl_xor(s.y, 32);
    s.z += __shfl_xor(s.z, 32);
    s.w += __shfl_xor(s.w, 32);

    const f32x4 rr = ((const f32x4*)(xrb + (size_t)i * HD))[cl];  // has +b1
    f32x4 h;
    h.x = fmaxf(fmaf(s.x, inv, rr.x), 0.f);
    h.y = fmaxf(fmaf(s.y, inv, rr.y), 0.f);
    h.z = fmaxf(fmaf(s.z, inv, rr.z), 0.f);
    h.w = fmaxf(fmaf(s.w, inv, rr.w), 0.f);

    const float4 w0 = wsm[cl * 4 + 0], w1 = wsm[cl * 4 + 1];
    const float4 w2 = wsm[cl * 4 + 2], w3 = wsm[cl * 4 + 3];
    const float4 q0 = wsm[128 + cl * 4 + 0], q1 = wsm[128 + cl * 4 + 1];
    const float4 q2 = wsm[128 + cl * 4 + 2], q3 = wsm[128 + cl * 4 + 3];
    float u0 = h.x * w0.x + h.y * w1.x + h.z * w2.x + h.w * w3.x;
    float u1 = h.x * w0.y + h.y * w1.y + h.z * w2.y + h.w * w3.y;
    float u2 = h.x * w0.z + h.y * w1.z + h.z * w2.z + h.w * w3.z;
    float v0 = h.x * q0.x + h.y * q1.x + h.z * q2.x + h.w * q3.x;
    float v1 = h.x * q0.y + h.y * q1.y + h.z * q2.y + h.w * q3.y;
    float v2 = h.x * q0.z + h.y * q1.z + h.z * q2.z + h.w * q3.z;
    #pragma unroll
    for (int off = 16; off; off >>= 1) {
        u0 += __shfl_xor(u0, off); u1 += __shfl_xor(u1, off); u2 += __shfl_xor(u2, off);
        v0 += __shfl_xor(v0, off); v1 += __shfl_xor(v1, off); v2 += __shfl_xor(v2, off);
    }
    if (lane == 0) {
        u4[i] = make_float4(u0, u1, u2, 0.f);
        v4[i] = make_float4(v0, v1, v2, 0.f);
    }
}

// ---------------------------------------------------------------------------
// K2: y[i] = mean_j u[j] + v[i] + c   (3-wide second-hop aggregation)
// ---------------------------------------------------------------------------
__global__ __launch_bounds__(256) void k_ycomb(
    const float4* __restrict__ u4, const float4* __restrict__ v4,
    const int* __restrict__ nbr, const int* __restrict__ degi,
    const float* __restrict__ degf, const float4* __restrict__ wsm,
    float4* __restrict__ y4)
{
    const int hw = threadIdx.x >> 5;
    const int lane = threadIdx.x & 31;
    const int i = blockIdx.x * 8 + hw;
    const int d = degi[i];
    const float inv = 1.0f / degf[i];
    const int* lst = nbr + (size_t)i * CAP;
    float s0 = 0.f, s1 = 0.f, s2 = 0.f;
    for (int base = 0; base + lane < d; base += 32) {
        const float4 u = u4[lst[base + lane]];
        s0 += u.x; s1 += u.y; s2 += u.z;
    }
    #pragma unroll
    for (int off = 16; off; off >>= 1) {
        s0 += __shfl_xor(s0, off); s1 += __shfl_xor(s1, off); s2 += __shfl_xor(s2, off);
    }
    if (lane == 0) {
        const float4 v = v4[i];
        const float4 c = wsm[256];
        y4[i] = make_float4(fmaf(s0, inv, v.x + c.x),
                            fmaf(s1, inv, v.y + c.y),
                            fmaf(s2, inv, v.z + c.z), 0.f);
    }
}

// ---------------------------------------------------------------------------
// K3: out[i,j] = ||y_i - y_j||, tiled 32 i x 1024 j per block.
// ---------------------------------------------------------------------------
__global__ __launch_bounds__(256) void k_cdist(
    const float4* __restrict__ y4, float* __restrict__ out)
{
    __shared__ float4 yis[32];
    const int t = threadIdx.x;
    const int i0 = blockIdx.y * 32;
    if (t < 32) yis[t] = y4[i0 + t];
    __syncthreads();
    const int j0 = blockIdx.x * 1024 + t * 4;
    const float4 a0 = y4[j0 + 0], a1 = y4[j0 + 1];
    const float4 a2 = y4[j0 + 2], a3 = y4[j0 + 3];
    float* op = out + (size_t)i0 * NN + j0;
    #pragma unroll 4
    for (int ii = 0; ii < 32; ++ii) {
        const float4 yi = yis[ii];
        f32x4 r;
        { const float dx = yi.x - a0.x, dy = yi.y - a0.y, dz = yi.z - a0.z;
          r.x = sqrtf(fmaf(dx, dx, fmaf(dy, dy, dz * dz))); }
        { const float dx = yi.x - a1.x, dy = yi.y - a1.y, dz = yi.z - a1.z;
          r.y = sqrtf(fmaf(dx, dx, fmaf(dy, dy, dz * dz))); }
        { const float dx = yi.x - a2.x, dy = yi.y - a2.y, dz = yi.z - a2.z;
          r.z = sqrtf(fmaf(dx, dx, fmaf(dy, dy, dz * dz))); }
        { const float dx = yi.x - a3.x, dy = yi.y - a3.y, dz = yi.z - a3.z;
          r.w = sqrtf(fmaf(dx, dx, fmaf(dy, dy, dz * dz))); }
        __builtin_nontemporal_store(r, (f32x4*)op);
        op += NN;
    }
}

// ---------------------------------------------------------------------------
extern "C" void kernel_launch(void* const* d_in, const int* in_sizes, int n_in,
                              void* d_out, int out_size, void* d_ws, size_t ws_size,
                              hipStream_t stream) {
    const float* x   = (const float*)d_in[0];
    const float* adj = (const float*)d_in[1];
    const float* Wl1 = (const float*)d_in[2];
    const float* Wr1 = (const float*)d_in[3];
    const float* b1  = (const float*)d_in[4];
    const float* Wl2 = (const float*)d_in[5];
    const float* Wr2 = (const float*)d_in[6];
    const float* b2  = (const float*)d_in[7];
    const float* Wd  = (const float*)d_in[8];
    const float* bd  = (const float*)d_in[9];
    float* out = (float*)d_out;

    // ---- workspace layout (16B-aligned slots) ----
    char* ws = (char*)d_ws;
    const size_t nbr_b  = (size_t)NN * CAP * 4;    // 4 MB
    const size_t deg_b  = (size_t)NN * 4;          // 32 KB each
    const size_t vec_b  = (size_t)NN * 16;         // 128 KB each (u4,v4,y4)
    const size_t wsm_b  = 272 * 16;
    const size_t small_total = nbr_b + 2 * deg_b + 3 * vec_b + wsm_b;
    const size_t xl_b = (size_t)NN * HD * 4;       // 4 MB each

    size_t off = 0;
    int*    nbr  = (int*)(ws + off);    off += nbr_b;
    int*    degi = (int*)(ws + off);    off += deg_b;
    float*  degf = (float*)(ws + off);  off += deg_b;
    float4* u4   = (float4*)(ws + off); off += vec_b;
    float4* v4   = (float4*)(ws + off); off += vec_b;
    float4* y4   = (float4*)(ws + off); off += vec_b;
    float4* wsm  = (float4*)(ws + off); off += wsm_b;

    // xl/xrb: in ws if it fits, else carve from d_out (dead before k_cdist).
    char* big = (ws_size >= small_total + 2 * xl_b) ? (ws + off) : (char*)d_out;
    float* xl  = (float*)(big);
    float* xrb = (float*)(big + xl_b);

    // ---- pipeline ----
    k_gemm<<<513, 256, 0, stream>>>(x, Wl1, Wr1, b1, Wl2, Wr2, b2, Wd, bd,
                                    xl, xrb, wsm);

    k_scanagg<<<NN / 4, 256, 0, stream>>>(adj, xl, xrb, wsm,
                                          nbr, degi, degf, u4, v4);

    k_ycomb<<<NN / 8, 256, 0, stream>>>(u4, v4, nbr, degi, degf, wsm, y4);

    k_cdist<<<dim3(NN / 1024, NN / 32), 256, 0, stream>>>(y4, out);
}